// Round 6
// baseline (97.553 us; speedup 1.0000x reference)
//
#include <hip/hip_runtime.h>

// Problem constants (B=1): inputs (N=32768, D=1024) f32, tag_to_token (T=128, N) f32,
// gat_mask (T, T) i32. Output (T, D) f32.
#define NTOK 32768
#define NTAG 128
#define DDIM 1024
#define TPB 32  // tokens per fused block

// ws layout:
//   P   : 128*1024 f32 = 524288 B (unscaled per-tag sums)
//   cnt : 128 i32      = 512 B

// ---------------------------------------------------------------------------
// Kernel 0: zero P and cnt (P receives atomics in k_fused, must be pre-zeroed).
// ---------------------------------------------------------------------------
__global__ __launch_bounds__(256) void k_zero(float* __restrict__ P,
                                              int* __restrict__ cnt) {
    const int gid = blockIdx.x * 256 + threadIdx.x;  // 32768 threads
    reinterpret_cast<float4*>(P)[gid] = make_float4(0.f, 0.f, 0.f, 0.f);
    if (gid < NTAG) cnt[gid] = 0;
}

// ---------------------------------------------------------------------------
// Kernel 1: fused tag-scan + segmented sum. Math fact: deduce_direct_string's
// temp[i][n] is 1 iff i is the LAST covering tag of n (for ANY 0/1 coverage),
// so the row-normalized t2t is one-hot per token / cnt[tag] -> the big matmul
// is a segmented sum of input rows into P[tag], scaled later by 1/cnt.
//
// Each block owns 32 tokens x all 1024 cols. Phase 1: compute the block's 32
// lastTags from t2t (thread (c=tid>>5, n=tid&31) scans 16 rows; 128B
// coalesced per 32-lane group; LDS max-reduce). Phase 2: stream the 32 input
// rows as two halves of 16 upfront float4 loads per thread (16 loads in
// flight, no register shuffling); run-length flush via atomicAdd into P on
// tag changes (wave-uniform branch); thread 0 adds run lengths to cnt.
// ---------------------------------------------------------------------------
__global__ __launch_bounds__(256) void k_fused(const float* __restrict__ inp,
                                               const float* __restrict__ t2t,
                                               float* __restrict__ P,
                                               int* __restrict__ cnt) {
    __shared__ int part[8][TPB];
    __shared__ int tags[TPB];
    const int tid = threadIdx.x;
    const int n0 = blockIdx.x * TPB;

    // ---- Phase 1: tags for this block's 32 tokens ----
    {
        const int c = tid >> 5;  // row chunk (16 rows)
        const int n = tid & 31;  // token within block
        int m = -1;
#pragma unroll
        for (int j = 0; j < 16; ++j) {
            const int r = c * 16 + j;
            if (t2t[(size_t)r * NTOK + n0 + n] > 0.f) m = r;
        }
        part[c][n] = m;
    }
    __syncthreads();
    if (tid < TPB) {
        int m = -1;
#pragma unroll
        for (int cc = 0; cc < 8; ++cc) m = max(m, part[cc][tid]);
        tags[tid] = m;
    }
    __syncthreads();

    // ---- Phase 2: stream 32 input rows, run-length flush ----
    const int col = tid * 4;
    const float4* src = reinterpret_cast<const float4*>(inp) + (size_t)n0 * 256 + tid;

    float4 acc = make_float4(0.f, 0.f, 0.f, 0.f);
    int cur = tags[0];
    int runlen = 0;

#pragma unroll
    for (int half = 0; half < 2; ++half) {
        float4 v[16];
#pragma unroll
        for (int k = 0; k < 16; ++k)
            v[k] = src[(size_t)(half * 16 + k) * 256];  // 16 loads in flight
#pragma unroll
        for (int k = 0; k < 16; ++k) {
            const int tg = tags[half * 16 + k];
            if (tg != cur) {  // wave-uniform (tags uniform across lanes)
                if (cur >= 0) {
                    float* p = P + (size_t)cur * DDIM + col;
                    atomicAdd(p + 0, acc.x);
                    atomicAdd(p + 1, acc.y);
                    atomicAdd(p + 2, acc.z);
                    atomicAdd(p + 3, acc.w);
                    if (tid == 0) atomicAdd(&cnt[cur], runlen);
                }
                acc = make_float4(0.f, 0.f, 0.f, 0.f);
                cur = tg;
                runlen = 0;
            }
            if (tg >= 0) {
                acc.x += v[k].x;
                acc.y += v[k].y;
                acc.z += v[k].z;
                acc.w += v[k].w;
                ++runlen;
            }
        }
    }
    if (cur >= 0) {
        float* p = P + (size_t)cur * DDIM + col;
        atomicAdd(p + 0, acc.x);
        atomicAdd(p + 1, acc.y);
        atomicAdd(p + 2, acc.z);
        atomicAdd(p + 3, acc.w);
        if (tid == 0) atomicAdd(&cnt[cur], runlen);
    }
}

// ---------------------------------------------------------------------------
// Kernel 2: triangular recurrence. deduce_child(gm) == gm for ANY input
// (inner loop provably a no-op: rows j>i are still zero at outer step i).
// o[i] = sum_t gm[i][t]*o_cur[t], i=127..0 -> independent per column d.
//
// One WAVE handles 4 columns via 16-lane groups (g=L>>4, l=L&15): group g
// owns column col0+g, lane l holds o[16k+l] in 8 VGPRs. Per step (unrolled,
// i literal): uniform ds_read of the 4-word row mask (independent of the
// compute chain -> pipelines ahead), per k: ubfe/cvt/fmac with per-lane
// shift (l or l+16), then 4 DPP adds entirely within the 16-lane row
// (xor1, xor2, half_mirror, mirror) -> ALL 16 lanes hold the total, update
// is a single cndmask. No ds_swizzle, no readlane, no cross-step LDS in the
// chain (~90cy/step vs ~300 before). 256 blocks x 1 wave = every CU busy.
// ---------------------------------------------------------------------------
template <int CTRL>
__device__ __forceinline__ float dpp_add(float x) {
    const int y = __builtin_amdgcn_update_dpp(0, __float_as_int(x), CTRL, 0xF, 0xF, true);
    return x + __int_as_float(y);
}

__global__ __launch_bounds__(64) void k_recur(const float* __restrict__ P,
                                              const int* __restrict__ gm,
                                              const int* __restrict__ cnt,
                                              float* __restrict__ out) {
    __shared__ unsigned rowmask[NTAG][4];  // 2 KB: row i's gm bits
    __shared__ float xpose[NTAG][4];       // 2 KB: transpose buffer (in & out)
    const int L = threadIdx.x;   // 0..63
    const int g = L >> 4;        // column group
    const int l = L & 15;        // sublane within group
    const int c0 = blockIdx.x * 4;

    // Build row masks via ballot (coalesced gm reads).
#pragma unroll 8
    for (int r = 0; r < NTAG; ++r) {
        const int a = gm[r * NTAG + L];
        const int b = gm[r * NTAG + 64 + L];
        const unsigned long long m0 = __ballot(a != 0);
        const unsigned long long m1 = __ballot(b != 0);
        if (L == 0) {
            rowmask[r][0] = (unsigned)m0;
            rowmask[r][1] = (unsigned)(m0 >> 32);
            rowmask[r][2] = (unsigned)m1;
            rowmask[r][3] = (unsigned)(m1 >> 32);
        }
    }

    // Load P rows L and 64+L (float4 each), scale by 1/cnt, transpose via LDS.
    const float ia = 1.0f / (float)cnt[L];
    const float ib = 1.0f / (float)cnt[64 + L];
    float4 pa = *reinterpret_cast<const float4*>(P + (size_t)L * DDIM + c0);
    float4 pb = *reinterpret_cast<const float4*>(P + (size_t)(64 + L) * DDIM + c0);
    xpose[L][0] = pa.x * ia;
    xpose[L][1] = pa.y * ia;
    xpose[L][2] = pa.z * ia;
    xpose[L][3] = pa.w * ia;
    xpose[64 + L][0] = pb.x * ib;
    xpose[64 + L][1] = pb.y * ib;
    xpose[64 + L][2] = pb.z * ib;
    xpose[64 + L][3] = pb.w * ib;
    __syncthreads();

    float o0 = xpose[l][g],        o1 = xpose[16 + l][g];
    float o2 = xpose[32 + l][g],   o3 = xpose[48 + l][g];
    float o4 = xpose[64 + l][g],   o5 = xpose[80 + l][g];
    float o6 = xpose[96 + l][g],   o7 = xpose[112 + l][g];

    const int sh0 = l;        // bit shift for even k
    const int sh1 = l + 16;   // bit shift for odd k

#pragma unroll
    for (int i = NTAG - 1; i >= 0; --i) {
        const uint4 rm = *reinterpret_cast<const uint4*>(rowmask[i]);  // uniform b128
        float s = 0.f;
        s += (float)((rm.x >> sh0) & 1u) * o0;
        s += (float)((rm.x >> sh1) & 1u) * o1;
        s += (float)((rm.y >> sh0) & 1u) * o2;
        s += (float)((rm.y >> sh1) & 1u) * o3;
        s += (float)((rm.z >> sh0) & 1u) * o4;
        s += (float)((rm.z >> sh1) & 1u) * o5;
        s += (float)((rm.w >> sh0) & 1u) * o6;
        s += (float)((rm.w >> sh1) & 1u) * o7;
        s = dpp_add<0xB1>(s);   // quad_perm xor1
        s = dpp_add<0x4E>(s);   // quad_perm xor2
        s = dpp_add<0x141>(s);  // row_half_mirror
        s = dpp_add<0x140>(s);  // row_mirror -> all 16 lanes have the total
        const bool mine = (l == (i & 15));
        switch (i >> 4) {  // i literal under full unroll -> static reg pick
            case 0: if (mine) o0 = s; break;
            case 1: if (mine) o1 = s; break;
            case 2: if (mine) o2 = s; break;
            case 3: if (mine) o3 = s; break;
            case 4: if (mine) o4 = s; break;
            case 5: if (mine) o5 = s; break;
            case 6: if (mine) o6 = s; break;
            case 7: if (mine) o7 = s; break;
        }
    }

    // Transpose back through LDS, store coalesced float4 rows.
    __syncthreads();
    xpose[l][g] = o0;        xpose[16 + l][g] = o1;
    xpose[32 + l][g] = o2;   xpose[48 + l][g] = o3;
    xpose[64 + l][g] = o4;   xpose[80 + l][g] = o5;
    xpose[96 + l][g] = o6;   xpose[112 + l][g] = o7;
    __syncthreads();
    float4 ra, rb;
    ra.x = xpose[L][0]; ra.y = xpose[L][1]; ra.z = xpose[L][2]; ra.w = xpose[L][3];
    rb.x = xpose[64 + L][0]; rb.y = xpose[64 + L][1];
    rb.z = xpose[64 + L][2]; rb.w = xpose[64 + L][3];
    *reinterpret_cast<float4*>(out + (size_t)L * DDIM + c0) = ra;
    *reinterpret_cast<float4*>(out + (size_t)(64 + L) * DDIM + c0) = rb;
}

// ---------------------------------------------------------------------------
extern "C" void kernel_launch(void* const* d_in, const int* in_sizes, int n_in,
                              void* d_out, int out_size, void* d_ws, size_t ws_size,
                              hipStream_t stream) {
    const float* inp = (const float*)d_in[0];  // (N, D)
    const float* t2t = (const float*)d_in[1];  // (T, N)
    const int* gm = (const int*)d_in[2];       // (T, T)
    float* out = (float*)d_out;                // (T, D)

    char* ws = (char*)d_ws;
    float* P = (float*)ws;           // 524288 B
    int* cnt = (int*)(ws + 524288);  // 512 B

    k_zero<<<128, 256, 0, stream>>>(P, cnt);
    k_fused<<<NTOK / TPB, 256, 0, stream>>>(inp, t2t, P, cnt);
    k_recur<<<DDIM / 4, 64, 0, stream>>>(P, gm, cnt, out);
}

// Round 7
// 54.277 us; speedup vs baseline: 1.7973x; 1.7973x over previous
//
#include <hip/hip_runtime.h>

// Problem constants (B=1): inputs (N=32768, D=1024) f32, tag_to_token (T=128, N) f32,
// gat_mask (T, T) i32. Output (T, D) f32.
#define NTOK 32768
#define NTAG 128
#define DDIM 1024
#define TPB 32  // tokens per fused block

// ws layout:
//   P     : 128*1024 f32 = 524288 B (unscaled per-tag sums)
//   cnt   : 128 i32      = 512 B
//   maskT : 32*16 u32    = 2048 B  (bit-transposed gm: word (k,iw), lane l,
//                                   bit ib = gm[iw*32+ib][16k+l])

// ---------------------------------------------------------------------------
// Kernel 0: zero P/cnt + build the bit-transposed gm mask table (block 0,
// 4 waves; wave wv handles rows iw=wv*32..+31 via 2 coalesced loads + 2
// ballots per row). maskT feeds k_recur's all-register recurrence.
// ---------------------------------------------------------------------------
__global__ __launch_bounds__(256) void k_zero(const int* __restrict__ gm,
                                              float* __restrict__ P,
                                              int* __restrict__ cnt,
                                              unsigned* __restrict__ maskT) {
    const int tid = threadIdx.x;
    const int gid = blockIdx.x * 256 + tid;
    reinterpret_cast<float4*>(P)[gid] = make_float4(0.f, 0.f, 0.f, 0.f);
    if (gid < NTAG) cnt[gid] = 0;

    if (blockIdx.x == 0) {
        const int wv = tid >> 6;    // 0..3 = word index iw
        const int lane = tid & 63;
        const int l = lane & 15;
        unsigned w0 = 0, w1 = 0, w2 = 0, w3 = 0, w4 = 0, w5 = 0, w6 = 0, w7 = 0;
        for (int ib = 0; ib < 32; ++ib) {
            const int i = wv * 32 + ib;
            const int a = gm[i * NTAG + lane];
            const int b = gm[i * NTAG + 64 + lane];
            const unsigned long long m0 = __ballot(a != 0);
            const unsigned long long m1 = __ballot(b != 0);
            w0 |= (unsigned)((m0 >> (l + 0)) & 1ull) << ib;
            w1 |= (unsigned)((m0 >> (l + 16)) & 1ull) << ib;
            w2 |= (unsigned)((m0 >> (l + 32)) & 1ull) << ib;
            w3 |= (unsigned)((m0 >> (l + 48)) & 1ull) << ib;
            w4 |= (unsigned)((m1 >> (l + 0)) & 1ull) << ib;
            w5 |= (unsigned)((m1 >> (l + 16)) & 1ull) << ib;
            w6 |= (unsigned)((m1 >> (l + 32)) & 1ull) << ib;
            w7 |= (unsigned)((m1 >> (l + 48)) & 1ull) << ib;
        }
        if (lane < 16) {
            maskT[(0 * 4 + wv) * 16 + l] = w0;
            maskT[(1 * 4 + wv) * 16 + l] = w1;
            maskT[(2 * 4 + wv) * 16 + l] = w2;
            maskT[(3 * 4 + wv) * 16 + l] = w3;
            maskT[(4 * 4 + wv) * 16 + l] = w4;
            maskT[(5 * 4 + wv) * 16 + l] = w5;
            maskT[(6 * 4 + wv) * 16 + l] = w6;
            maskT[(7 * 4 + wv) * 16 + l] = w7;
        }
    }
}

// ---------------------------------------------------------------------------
// Kernel 1: fused tag-scan + segmented sum (unchanged from round 6 — it runs
// at ~15us, near the L3-warm streaming floor for 144 MB).
// Math fact: deduce_direct_string's temp[i][n] is 1 iff i is the LAST
// covering tag of n (for ANY 0/1 coverage), so the row-normalized t2t is
// one-hot per token / cnt[tag] -> the big matmul is a segmented sum.
// ---------------------------------------------------------------------------
__global__ __launch_bounds__(256) void k_fused(const float* __restrict__ inp,
                                               const float* __restrict__ t2t,
                                               float* __restrict__ P,
                                               int* __restrict__ cnt) {
    __shared__ int part[8][TPB];
    __shared__ int tags[TPB];
    const int tid = threadIdx.x;
    const int n0 = blockIdx.x * TPB;

    {
        const int c = tid >> 5;  // row chunk (16 rows)
        const int n = tid & 31;  // token within block
        int m = -1;
#pragma unroll
        for (int j = 0; j < 16; ++j) {
            const int r = c * 16 + j;
            if (t2t[(size_t)r * NTOK + n0 + n] > 0.f) m = r;
        }
        part[c][n] = m;
    }
    __syncthreads();
    if (tid < TPB) {
        int m = -1;
#pragma unroll
        for (int cc = 0; cc < 8; ++cc) m = max(m, part[cc][tid]);
        tags[tid] = m;
    }
    __syncthreads();

    const int col = tid * 4;
    const float4* src = reinterpret_cast<const float4*>(inp) + (size_t)n0 * 256 + tid;

    float4 acc = make_float4(0.f, 0.f, 0.f, 0.f);
    int cur = tags[0];
    int runlen = 0;

#pragma unroll
    for (int half = 0; half < 2; ++half) {
        float4 v[16];
#pragma unroll
        for (int k = 0; k < 16; ++k)
            v[k] = src[(size_t)(half * 16 + k) * 256];  // 16 loads in flight
#pragma unroll
        for (int k = 0; k < 16; ++k) {
            const int tg = tags[half * 16 + k];
            if (tg != cur) {  // wave-uniform (tags uniform across lanes)
                if (cur >= 0) {
                    float* p = P + (size_t)cur * DDIM + col;
                    atomicAdd(p + 0, acc.x);
                    atomicAdd(p + 1, acc.y);
                    atomicAdd(p + 2, acc.z);
                    atomicAdd(p + 3, acc.w);
                    if (tid == 0) atomicAdd(&cnt[cur], runlen);
                }
                acc = make_float4(0.f, 0.f, 0.f, 0.f);
                cur = tg;
                runlen = 0;
            }
            if (tg >= 0) {
                acc.x += v[k].x;
                acc.y += v[k].y;
                acc.z += v[k].z;
                acc.w += v[k].w;
                ++runlen;
            }
        }
    }
    if (cur >= 0) {
        float* p = P + (size_t)cur * DDIM + col;
        atomicAdd(p + 0, acc.x);
        atomicAdd(p + 1, acc.y);
        atomicAdd(p + 2, acc.z);
        atomicAdd(p + 3, acc.w);
        if (tid == 0) atomicAdd(&cnt[cur], runlen);
    }
}

// ---------------------------------------------------------------------------
// Kernel 2: triangular recurrence, all-register. deduce_child(gm) == gm for
// ANY input (inner loop provably a no-op). o[i] = sum_t gm[i][t]*o_cur[t],
// i=127..0, independent per column d. One wave = 4 columns (16-lane groups);
// lane l of group g holds o[16k+l] (8 VGPRs) of column c0+g; gm bits live in
// 32 VGPRs (mw[k][iw], bit ib = gm[iw*32+ib][16k+l], from maskT). Per step:
// 8x shift/and/cvt/fmac + 4 DPP adds (xor1,xor2,half_mirror,mirror -> all 16
// lanes hold the total) + 1 guarded move. NO memory access in the loop, and
// NO full unroll (8 sections x 16-iter runtime loops, ~6KB code, I-cache
// resident) -- round 6's 1480cy/step came from per-step LDS reads + 50KB of
// unrolled code thrashing L1I with a single resident wave.
// ---------------------------------------------------------------------------
template <int CTRL>
__device__ __forceinline__ float dpp_add(float x) {
    const int y = __builtin_amdgcn_update_dpp(0, __float_as_int(x), CTRL, 0xF, 0xF, true);
    return x + __int_as_float(y);
}

__global__ __launch_bounds__(64) void k_recur(const float* __restrict__ P,
                                              const unsigned* __restrict__ maskT,
                                              const int* __restrict__ cnt,
                                              float* __restrict__ out) {
    __shared__ float xpose[NTAG][4];  // 2 KB transpose buffer (in & out)
    const int L = threadIdx.x;  // 0..63
    const int g = L >> 4;       // column group
    const int l = L & 15;       // sublane (t-slot)
    const int c0 = blockIdx.x * 4;

    // 32 mask words per lane (static indices via full unroll of k,iw).
    unsigned mw[8][4];
#pragma unroll
    for (int k = 0; k < 8; ++k)
#pragma unroll
        for (int iw = 0; iw < 4; ++iw) mw[k][iw] = maskT[(k * 4 + iw) * 16 + l];

    // Load P rows L and 64+L, scale by 1/cnt, transpose via LDS.
    const float ia = 1.0f / (float)cnt[L];
    const float ib_ = 1.0f / (float)cnt[64 + L];
    float4 pa = *reinterpret_cast<const float4*>(P + (size_t)L * DDIM + c0);
    float4 pb = *reinterpret_cast<const float4*>(P + (size_t)(64 + L) * DDIM + c0);
    xpose[L][0] = pa.x * ia;
    xpose[L][1] = pa.y * ia;
    xpose[L][2] = pa.z * ia;
    xpose[L][3] = pa.w * ia;
    xpose[64 + L][0] = pb.x * ib_;
    xpose[64 + L][1] = pb.y * ib_;
    xpose[64 + L][2] = pb.z * ib_;
    xpose[64 + L][3] = pb.w * ib_;
    __syncthreads();

    float o0 = xpose[l][g], o1 = xpose[16 + l][g];
    float o2 = xpose[32 + l][g], o3 = xpose[48 + l][g];
    float o4 = xpose[64 + l][g], o5 = xpose[80 + l][g];
    float o6 = xpose[96 + l][g], o7 = xpose[112 + l][g];

    // Section: rows i = IW*32 + ib for ib in [IBLO, IBHI], update slot oKU
    // (KU = i>>4 is constant per section; l == (ib & 15) picks the lane).
#define SECTION(IW, KU, IBHI, IBLO)                                         \
    _Pragma("unroll 2") for (int ib = IBHI; ib >= IBLO; --ib) {             \
        float sa = (float)((mw[0][IW] >> ib) & 1u) * o0;                    \
        sa += (float)((mw[1][IW] >> ib) & 1u) * o1;                         \
        sa += (float)((mw[2][IW] >> ib) & 1u) * o2;                         \
        sa += (float)((mw[3][IW] >> ib) & 1u) * o3;                         \
        float sb = (float)((mw[4][IW] >> ib) & 1u) * o4;                    \
        sb += (float)((mw[5][IW] >> ib) & 1u) * o5;                         \
        sb += (float)((mw[6][IW] >> ib) & 1u) * o6;                         \
        sb += (float)((mw[7][IW] >> ib) & 1u) * o7;                         \
        float s = sa + sb;                                                  \
        s = dpp_add<0xB1>(s);  /* quad_perm xor1 */                         \
        s = dpp_add<0x4E>(s);  /* quad_perm xor2 */                         \
        s = dpp_add<0x141>(s); /* row_half_mirror */                        \
        s = dpp_add<0x140>(s); /* row_mirror: 16-lane total in all lanes */ \
        if (l == (ib & 15)) o##KU = s;                                      \
    }

    SECTION(3, 7, 31, 16)
    SECTION(3, 6, 15, 0)
    SECTION(2, 5, 31, 16)
    SECTION(2, 4, 15, 0)
    SECTION(1, 3, 31, 16)
    SECTION(1, 2, 15, 0)
    SECTION(0, 1, 31, 16)
    SECTION(0, 0, 15, 0)
#undef SECTION

    // Transpose back through LDS, store coalesced float4 rows.
    __syncthreads();
    xpose[l][g] = o0;
    xpose[16 + l][g] = o1;
    xpose[32 + l][g] = o2;
    xpose[48 + l][g] = o3;
    xpose[64 + l][g] = o4;
    xpose[80 + l][g] = o5;
    xpose[96 + l][g] = o6;
    xpose[112 + l][g] = o7;
    __syncthreads();
    float4 ra, rb;
    ra.x = xpose[L][0];
    ra.y = xpose[L][1];
    ra.z = xpose[L][2];
    ra.w = xpose[L][3];
    rb.x = xpose[64 + L][0];
    rb.y = xpose[64 + L][1];
    rb.z = xpose[64 + L][2];
    rb.w = xpose[64 + L][3];
    *reinterpret_cast<float4*>(out + (size_t)L * DDIM + c0) = ra;
    *reinterpret_cast<float4*>(out + (size_t)(64 + L) * DDIM + c0) = rb;
}

// ---------------------------------------------------------------------------
extern "C" void kernel_launch(void* const* d_in, const int* in_sizes, int n_in,
                              void* d_out, int out_size, void* d_ws, size_t ws_size,
                              hipStream_t stream) {
    const float* inp = (const float*)d_in[0];  // (N, D)
    const float* t2t = (const float*)d_in[1];  // (T, N)
    const int* gm = (const int*)d_in[2];       // (T, T)
    float* out = (float*)d_out;                // (T, D)

    char* ws = (char*)d_ws;
    float* P = (float*)ws;                        // 524288 B
    int* cnt = (int*)(ws + 524288);               // 512 B
    unsigned* maskT = (unsigned*)(ws + 524800);   // 2048 B

    k_zero<<<128, 256, 0, stream>>>(gm, P, cnt, maskT);
    k_fused<<<NTOK / TPB, 256, 0, stream>>>(inp, t2t, P, cnt);
    k_recur<<<DDIM / 4, 64, 0, stream>>>(P, maskT, cnt, out);
}

// Round 8
// 51.156 us; speedup vs baseline: 1.9070x; 1.0610x over previous
//
#include <hip/hip_runtime.h>

// Problem constants (B=1): inputs (N=32768, D=1024) f32, tag_to_token (T=128, N) f32,
// gat_mask (T, T) i32. Output (T, D) f32.
#define NTOK 32768
#define NTAG 128
#define DDIM 1024
#define TPB 32  // tokens per fused block

// ws layout:
//   P     : 128*1024 f32 = 524288 B (unscaled per-tag sums)
//   cnt   : 128 i32      = 512 B
//   maskT : 32*16 u32    = 2048 B  (bit-transposed gm: word (k,iw), lane l,
//                                   bit ib = gm[iw*32+ib][16k+l])

// ---------------------------------------------------------------------------
// Kernel 0: zero P/cnt; blocks 1-2 additionally build the bit-transposed gm
// mask table as a 512-thread GATHER: thread (k,iw,l) reads its 32 strided
// ints with a fully-unrolled loop (all loads in flight) and writes one word.
// (Round 7 built this with a 32-iteration 1-wave loop of dependent-waited
// loads+ballots -> ~10us serial prologue blocking k_fused. This is ~0.5us.)
// ---------------------------------------------------------------------------
__global__ __launch_bounds__(256) void k_zero(const int* __restrict__ gm,
                                              float* __restrict__ P,
                                              int* __restrict__ cnt,
                                              unsigned* __restrict__ maskT) {
    const int tid = threadIdx.x;
    const int gid = blockIdx.x * 256 + tid;
    reinterpret_cast<float4*>(P)[gid] = make_float4(0.f, 0.f, 0.f, 0.f);
    if (gid < NTAG) cnt[gid] = 0;

    if (blockIdx.x == 1 || blockIdx.x == 2) {
        const int idx = (blockIdx.x - 1) * 256 + tid;  // 0..511 = (k*4+iw)*16+l
        const int l = idx & 15;
        const int iw = (idx >> 4) & 3;
        const int k = idx >> 6;
        const int colg = 16 * k + l;  // gm column this word tracks
        unsigned w = 0;
#pragma unroll
        for (int ib = 0; ib < 32; ++ib)
            w |= (unsigned)(gm[(iw * 32 + ib) * NTAG + colg] != 0) << ib;
        maskT[idx] = w;
    }
}

// ---------------------------------------------------------------------------
// Kernel 1: fused tag-scan + segmented sum (unchanged — near the HBM/L3
// streaming floor for its 144 MB). Math fact: deduce_direct_string's
// temp[i][n] is 1 iff i is the LAST covering tag of n (for ANY 0/1
// coverage), so the row-normalized t2t is one-hot per token / cnt[tag] ->
// the big matmul is a segmented sum into P[tag], scaled later by 1/cnt.
// ---------------------------------------------------------------------------
__global__ __launch_bounds__(256) void k_fused(const float* __restrict__ inp,
                                               const float* __restrict__ t2t,
                                               float* __restrict__ P,
                                               int* __restrict__ cnt) {
    __shared__ int part[8][TPB];
    __shared__ int tags[TPB];
    const int tid = threadIdx.x;
    const int n0 = blockIdx.x * TPB;

    {
        const int c = tid >> 5;  // row chunk (16 rows)
        const int n = tid & 31;  // token within block
        int m = -1;
#pragma unroll
        for (int j = 0; j < 16; ++j) {
            const int r = c * 16 + j;
            if (t2t[(size_t)r * NTOK + n0 + n] > 0.f) m = r;
        }
        part[c][n] = m;
    }
    __syncthreads();
    if (tid < TPB) {
        int m = -1;
#pragma unroll
        for (int cc = 0; cc < 8; ++cc) m = max(m, part[cc][tid]);
        tags[tid] = m;
    }
    __syncthreads();

    const int col = tid * 4;
    const float4* src = reinterpret_cast<const float4*>(inp) + (size_t)n0 * 256 + tid;

    float4 acc = make_float4(0.f, 0.f, 0.f, 0.f);
    int cur = tags[0];
    int runlen = 0;

#pragma unroll
    for (int half = 0; half < 2; ++half) {
        float4 v[16];
#pragma unroll
        for (int k = 0; k < 16; ++k)
            v[k] = src[(size_t)(half * 16 + k) * 256];  // 16 loads in flight
#pragma unroll
        for (int k = 0; k < 16; ++k) {
            const int tg = tags[half * 16 + k];
            if (tg != cur) {  // wave-uniform (tags uniform across lanes)
                if (cur >= 0) {
                    float* p = P + (size_t)cur * DDIM + col;
                    atomicAdd(p + 0, acc.x);
                    atomicAdd(p + 1, acc.y);
                    atomicAdd(p + 2, acc.z);
                    atomicAdd(p + 3, acc.w);
                    if (tid == 0) atomicAdd(&cnt[cur], runlen);
                }
                acc = make_float4(0.f, 0.f, 0.f, 0.f);
                cur = tg;
                runlen = 0;
            }
            if (tg >= 0) {
                acc.x += v[k].x;
                acc.y += v[k].y;
                acc.z += v[k].z;
                acc.w += v[k].w;
                ++runlen;
            }
        }
    }
    if (cur >= 0) {
        float* p = P + (size_t)cur * DDIM + col;
        atomicAdd(p + 0, acc.x);
        atomicAdd(p + 1, acc.y);
        atomicAdd(p + 2, acc.z);
        atomicAdd(p + 3, acc.w);
        if (tid == 0) atomicAdd(&cnt[cur], runlen);
    }
}

// ---------------------------------------------------------------------------
// Kernel 2: triangular recurrence, all-register. deduce_child(gm) == gm for
// ANY input (inner loop provably a no-op). o[i] = sum_t gm[i][t]*o_cur[t],
// i=127..0, independent per column d. One wave = 4 columns (16-lane groups);
// lane l of group g holds o[16k+l] (8 VGPRs); gm bits in 32 VGPRs from
// maskT. Per step: 8x shift/and/cvt/fmac + 4 DPP adds (xor1, xor2,
// half_mirror, mirror -> all 16 lanes hold the total) + 1 guarded move.
// No memory in the loop; ~6KB body (8 sections x 16-iter runtime loops) so
// L1I-resident -- R6's 79us was traced to the 50KB fully-unrolled body
// missing I-cache every step with a single resident wave.
// xpose padded [128][5] to kill the 8-way bank conflict in the transposes.
// ---------------------------------------------------------------------------
template <int CTRL>
__device__ __forceinline__ float dpp_add(float x) {
    const int y = __builtin_amdgcn_update_dpp(0, __float_as_int(x), CTRL, 0xF, 0xF, true);
    return x + __int_as_float(y);
}

__global__ __launch_bounds__(64) void k_recur(const float* __restrict__ P,
                                              const unsigned* __restrict__ maskT,
                                              const int* __restrict__ cnt,
                                              float* __restrict__ out) {
    __shared__ float xpose[NTAG][5];  // padded: stride 5 coprime 32 banks
    const int L = threadIdx.x;  // 0..63
    const int g = L >> 4;       // column group
    const int l = L & 15;       // sublane (t-slot)
    const int c0 = blockIdx.x * 4;

    // 32 mask words per lane (static indices via full unroll of k,iw).
    unsigned mw[8][4];
#pragma unroll
    for (int k = 0; k < 8; ++k)
#pragma unroll
        for (int iw = 0; iw < 4; ++iw) mw[k][iw] = maskT[(k * 4 + iw) * 16 + l];

    // Load P rows L and 64+L, scale by 1/cnt, transpose via LDS.
    const float ia = 1.0f / (float)cnt[L];
    const float ib_ = 1.0f / (float)cnt[64 + L];
    float4 pa = *reinterpret_cast<const float4*>(P + (size_t)L * DDIM + c0);
    float4 pb = *reinterpret_cast<const float4*>(P + (size_t)(64 + L) * DDIM + c0);
    xpose[L][0] = pa.x * ia;
    xpose[L][1] = pa.y * ia;
    xpose[L][2] = pa.z * ia;
    xpose[L][3] = pa.w * ia;
    xpose[64 + L][0] = pb.x * ib_;
    xpose[64 + L][1] = pb.y * ib_;
    xpose[64 + L][2] = pb.z * ib_;
    xpose[64 + L][3] = pb.w * ib_;
    __syncthreads();

    float o0 = xpose[l][g], o1 = xpose[16 + l][g];
    float o2 = xpose[32 + l][g], o3 = xpose[48 + l][g];
    float o4 = xpose[64 + l][g], o5 = xpose[80 + l][g];
    float o6 = xpose[96 + l][g], o7 = xpose[112 + l][g];

    // Section: rows i = IW*32 + ib for ib in [IBLO, IBHI], update slot oKU
    // (KU = i>>4 constant per section; l == (ib & 15) picks the lane).
#define SECTION(IW, KU, IBHI, IBLO)                                         \
    _Pragma("unroll 2") for (int ib = IBHI; ib >= IBLO; --ib) {             \
        float sa = (float)((mw[0][IW] >> ib) & 1u) * o0;                    \
        sa += (float)((mw[1][IW] >> ib) & 1u) * o1;                         \
        sa += (float)((mw[2][IW] >> ib) & 1u) * o2;                         \
        sa += (float)((mw[3][IW] >> ib) & 1u) * o3;                         \
        float sb = (float)((mw[4][IW] >> ib) & 1u) * o4;                    \
        sb += (float)((mw[5][IW] >> ib) & 1u) * o5;                         \
        sb += (float)((mw[6][IW] >> ib) & 1u) * o6;                         \
        sb += (float)((mw[7][IW] >> ib) & 1u) * o7;                         \
        float s = sa + sb;                                                  \
        s = dpp_add<0xB1>(s);  /* quad_perm xor1 */                         \
        s = dpp_add<0x4E>(s);  /* quad_perm xor2 */                         \
        s = dpp_add<0x141>(s); /* row_half_mirror */                        \
        s = dpp_add<0x140>(s); /* row_mirror: 16-lane total in all lanes */ \
        if (l == (ib & 15)) o##KU = s;                                      \
    }

    SECTION(3, 7, 31, 16)
    SECTION(3, 6, 15, 0)
    SECTION(2, 5, 31, 16)
    SECTION(2, 4, 15, 0)
    SECTION(1, 3, 31, 16)
    SECTION(1, 2, 15, 0)
    SECTION(0, 1, 31, 16)
    SECTION(0, 0, 15, 0)
#undef SECTION

    // Transpose back through LDS, store coalesced float4 rows.
    __syncthreads();
    xpose[l][g] = o0;
    xpose[16 + l][g] = o1;
    xpose[32 + l][g] = o2;
    xpose[48 + l][g] = o3;
    xpose[64 + l][g] = o4;
    xpose[80 + l][g] = o5;
    xpose[96 + l][g] = o6;
    xpose[112 + l][g] = o7;
    __syncthreads();
    float4 ra, rb;
    ra.x = xpose[L][0];
    ra.y = xpose[L][1];
    ra.z = xpose[L][2];
    ra.w = xpose[L][3];
    rb.x = xpose[64 + L][0];
    rb.y = xpose[64 + L][1];
    rb.z = xpose[64 + L][2];
    rb.w = xpose[64 + L][3];
    *reinterpret_cast<float4*>(out + (size_t)L * DDIM + c0) = ra;
    *reinterpret_cast<float4*>(out + (size_t)(64 + L) * DDIM + c0) = rb;
}

// ---------------------------------------------------------------------------
extern "C" void kernel_launch(void* const* d_in, const int* in_sizes, int n_in,
                              void* d_out, int out_size, void* d_ws, size_t ws_size,
                              hipStream_t stream) {
    const float* inp = (const float*)d_in[0];  // (N, D)
    const float* t2t = (const float*)d_in[1];  // (T, N)
    const int* gm = (const int*)d_in[2];       // (T, T)
    float* out = (float*)d_out;                // (T, D)

    char* ws = (char*)d_ws;
    float* P = (float*)ws;                       // 524288 B
    int* cnt = (int*)(ws + 524288);              // 512 B
    unsigned* maskT = (unsigned*)(ws + 524800);  // 2048 B

    k_zero<<<128, 256, 0, stream>>>(gm, P, cnt, maskT);
    k_fused<<<NTOK / TPB, 256, 0, stream>>>(inp, t2t, P, cnt);
    k_recur<<<DDIM / 4, 64, 0, stream>>>(P, maskT, cnt, out);
}